// Round 18
// baseline (2564.296 us; speedup 1.0000x reference)
//
#include <hip/hip_runtime.h>
#include <math.h>

#define B_   8
#define CH   64
#define H_   256
#define W_   256
#define NPIX (H_*W_)        // 65536
#define NIMG (B_*NPIX)      // 524288
#define NBLK 4096           // body-conv blocks (16x8 px tiles)
#define PS   16             // LDS pixel stride in dwords (uniform bank spread)

typedef short bf16x8 __attribute__((ext_vector_type(8)));
typedef float f32x4  __attribute__((ext_vector_type(4)));
typedef float f32x16 __attribute__((ext_vector_type(16)));

// persistent device-side scratch (outside ws; recomputed every launch)
__device__ float g_stats[256];        // [128..191] a, [192..255] b
__device__ float g_part[128 * NBLK];  // per-block BN partials, [slot][block]
// packed A-frags for 32x32x16: [l][36 k16-slices][2 octiles][64 lanes][8hi+8lo]
__device__ __align__(16) short g_wpk[15 * 36 * 2 * 64 * 16];

// ---------------------------------------------------------------------------
// helpers
// ---------------------------------------------------------------------------
__device__ __forceinline__ int refl(int i) {
    if (i < 0)    return -i;
    if (i >= 256) return 510 - i;
    return i;
}
__device__ __forceinline__ float prep1(float v) {
    float xn = fminf(fmaxf((v + 1.0f) * 0.5f, 1e-6f), 1.0f);
    return 0.6f * xn + 0.4f * xn * sqrtf(xn);
}
__device__ __forceinline__ unsigned short bf16_rne(float f) {
    union { float f; unsigned u; } v; v.f = f;
    unsigned r = v.u + 0x7FFFu + ((v.u >> 16) & 1u);
    return (unsigned short)(r >> 16);
}
__device__ __forceinline__ float bf16_f(unsigned short h) {
    union { float f; unsigned u; } v; v.u = ((unsigned)h) << 16;
    return v.f;
}
// pack 2 f32 -> 2 bf16 in one instr (src0 -> low half)
__device__ __forceinline__ unsigned cvt_pk_bf16(float a, float b) {
    unsigned r;
    asm volatile("v_cvt_pk_bf16_f32 %0, %1, %2" : "=v"(r) : "v"(a), "v"(b));
    return r;
}
// barrier that does NOT drain vmcnt; LDS visibility needs only lgkmcnt(0).
__device__ __forceinline__ void bar_lds() {
    asm volatile("s_waitcnt lgkmcnt(0)" ::: "memory");
    __builtin_amdgcn_s_barrier();
}

// ---------------------------------------------------------------------------
// init affine: a=1, b=0
// ---------------------------------------------------------------------------
__global__ void init_ab_kernel() {
    int c = threadIdx.x;            // 64
    g_stats[128 + c] = 1.0f;
    g_stats[192 + c] = 0.0f;
}

// ---------------------------------------------------------------------------
// weight prepack for 32x32x16 A-frags, split bf16 hi/lo.
// k = t*64 + ic; k16-slice ss = t*4 + icq (icq in 0..3, ic = icq*16 + ...).
// A frag (32x32x16): lane: row(oc) = mt*32 + (lane&31), k = (lane>>5)*8 + j
// ---------------------------------------------------------------------------
__global__ void prepack_kernel(const float* __restrict__ w_body) {
    int idx = blockIdx.x * 256 + threadIdx.x;
    if (idx >= 15*36*2*64) return;
    int lane = idx & 63;
    int mt   = (idx >> 6) & 1;
    int r2   = idx >> 7;            // l*36 + ss
    int l    = r2 / 36;
    int ss   = r2 - l * 36;
    int t   = ss >> 2;
    int icq = ss & 3;
    int oc  = mt * 32 + (lane & 31);
    int icb = icq * 16 + (lane >> 5) * 8;
    union { short s[8]; int4 v; } uh, ul;
    #pragma unroll
    for (int j = 0; j < 8; ++j) {
        float w = w_body[(((size_t)l * 64 + oc) * 64 + (icb + j)) * 9 + t];
        unsigned short h = bf16_rne(w);
        unsigned short lo = bf16_rne(w - bf16_f(h));
        uh.s[j] = (short)h;
        ul.s[j] = (short)lo;
    }
    int4* dst = (int4*)(g_wpk + (size_t)idx * 16);
    dst[0] = uh.v;
    dst[1] = ul.v;
}

// ---------------------------------------------------------------------------
// init conv: xpre (prep+bilateral inline) -> 1->64ch 3x3 SAME, ReLU
// output NHWC: h[(b*NPIX + y*W + x)*64 + c]
// ---------------------------------------------------------------------------
__global__ __launch_bounds__(256) void conv_init_kernel(
    const float* __restrict__ x, const float* __restrict__ wi,
    float* __restrict__ h)
{
    __shared__ float s_bl[14][38];
    __shared__ float s_xp[10][34];
    __shared__ float s_w[64 * 12];    // padded rows of 12 for aligned b128
    int bx = blockIdx.x, by = blockIdx.y, b = blockIdx.z;
    int tid = threadIdx.x;
    const float* xb = x + b * NPIX;

    for (int i = tid; i < 14*38; i += 256) {
        int r = i / 38, c = i - r * 38;
        int gy = refl(by * 8 + r - 3), gx = refl(bx * 32 + c - 3);
        s_bl[r][c] = prep1(xb[gy * W_ + gx]);
    }
    for (int i = tid; i < 576; i += 256) {
        int oc = i / 9, t = i - oc * 9;
        s_w[oc * 12 + t] = wi[i];
    }
    __syncthreads();

    for (int i = tid; i < 10*34; i += 256) {
        int r = i / 34, c = i - r * 34;
        int gy = by * 8 + r - 1, gx = bx * 32 + c - 1;
        float v = 0.f;
        if (gy >= 0 && gy < H_ && gx >= 0 && gx < W_) {
            float ctr = s_bl[r + 2][c + 2];
            float num = 0.f, den = 0.f;
            #pragma unroll
            for (int dy = -2; dy <= 2; ++dy)
                #pragma unroll
                for (int dx = -2; dx <= 2; ++dx) {
                    float nb = s_bl[r + 2 + dy][c + 2 + dx];
                    float d  = nb - ctr;
                    float wgt = expf(-(float)(dy*dy + dx*dx) * 2e-4f - d * d * 200.0f);
                    num += wgt * nb;
                    den += wgt;
                }
            v = num / den;
        }
        s_xp[r][c] = v;
    }
    __syncthreads();

    int px = tid & 31, py = tid >> 5;
    float v[9];
    #pragma unroll
    for (int dr = 0; dr < 3; ++dr)
        #pragma unroll
        for (int dc = 0; dc < 3; ++dc)
            v[dr*3+dc] = s_xp[py + dr][px + dc];

    float acc[64];
    #pragma unroll
    for (int oc = 0; oc < 64; ++oc) {
        f32x4 w0 = *(const f32x4*)&s_w[oc * 12];
        f32x4 w1 = *(const f32x4*)&s_w[oc * 12 + 4];
        float w8 = s_w[oc * 12 + 8];
        float a = w0[0]*v[0] + w0[1]*v[1] + w0[2]*v[2] + w0[3]*v[3];
        a += w1[0]*v[4] + w1[1]*v[5] + w1[2]*v[6] + w1[3]*v[7];
        a = fmaf(w8, v[8], a);
        acc[oc] = fmaxf(a, 0.f);
    }

    int gy = by * 8 + py, gx = bx * 32 + px;
    float* outp = h + ((size_t)(b * NPIX + gy * W_ + gx)) * 64;
    #pragma unroll
    for (int c4 = 0; c4 < 16; ++c4) {
        float4 o = make_float4(acc[4*c4], acc[4*c4+1], acc[4*c4+2], acc[4*c4+3]);
        *reinterpret_cast<float4*>(outp + 4*c4) = o;
    }
}

// ---------------------------------------------------------------------------
// body conv via 32x32x16 MFMA implicit GEMM, split-bf16 (3-term), NHWC.
// block: 16x8 px x 64 oc; wave wv: px rows {2wv, 2wv+1} x 64 oc (32 px/wave,
// one MFMA N=32 column block). Per (tap, k16-slice): 2 oc-tiles x 3 terms = 6
// MFMAs of 32x32x16 (2x FLOP/instr, 2495 TF rate vs 2176 for 16x16x32).
// LDS act layout unchanged: [p][16 dwords], PS=16 conflict-free, 23 KB.
// ---------------------------------------------------------------------------
__global__ __launch_bounds__(256, 4) void conv_body_mfma(
    const float* __restrict__ hin, int l, float* __restrict__ hout)
{
    __shared__ unsigned s_hi[180 * PS];   // 11520 B (reused as s_red at end)
    __shared__ unsigned s_lo[180 * PS];   // 11520 B

    int tid  = threadIdx.x;
    int lane = tid & 63;
    int wv   = tid >> 6;

    // XCD swizzle: 4096 blocks / 8 XCDs -> one image per XCD
    int bid = blockIdx.x;
    int swz = (bid & 7) * 512 + (bid >> 3);
    int bx = swz & 15;            // 16 x-tiles of 16
    int by = (swz >> 4) & 31;     // 32 y-tiles of 8
    int b  = swz >> 9;            // 8 images

    const float* ab = &g_stats[128];
    int q   = tid & 7;          // channel quad (fixed per thread)
    int c0  = q * 4;            // ch offset within 32-ch chunk
    int pr0 = tid >> 3;         // pixel base for staging (0..31)

    f32x16 acc2[2];
    acc2[0] = (f32x16){0.f,0.f,0.f,0.f,0.f,0.f,0.f,0.f,0.f,0.f,0.f,0.f,0.f,0.f,0.f,0.f};
    acc2[1] = acc2[0];

    // split 4 fp32 -> hi/lo bf16 pairs and store to LDS
    auto split_store = [&](int p, float v0, float v1, float v2, float v3) {
        unsigned hh0 = cvt_pk_bf16(v0, v1);
        unsigned hh1 = cvt_pk_bf16(v2, v3);
        float f0 = __uint_as_float(hh0 << 16);
        float f1 = __uint_as_float(hh0 & 0xffff0000u);
        float f2 = __uint_as_float(hh1 << 16);
        float f3 = __uint_as_float(hh1 & 0xffff0000u);
        unsigned ll0 = cvt_pk_bf16(v0 - f0, v1 - f1);
        unsigned ll1 = cvt_pk_bf16(v2 - f2, v3 - f3);
        *(uint2*)&s_hi[p * PS + 2*q] = make_uint2(hh0, hh1);
        *(uint2*)&s_lo[p * PS + 2*q] = make_uint2(ll0, ll1);
    };

    // ---- stage a 32-ch chunk (edge-safe path) ----
    auto stage_safe = [&](int chunk) {
        float4 a4 = *(const float4*)&ab[chunk * 32 + c0];
        float4 b4 = *(const float4*)&ab[64 + chunk * 32 + c0];
        #pragma unroll
        for (int k = 0; k < 6; ++k) {
            int p = k * 32 + pr0;
            if (p < 180) {
                int y = p / 18, xx = p - y * 18;
                int gy = by * 8 + y - 1, gx = bx * 16 + xx - 1;
                bool inb = (gy >= 0 && gy < H_ && gx >= 0 && gx < W_);
                const float4* src = (const float4*)(
                    hin + ((size_t)(b * NPIX + (inb ? gy * W_ + gx : 0))) * 64 + chunk * 32 + c0);
                float4 v = *src;
                float v0 = inb ? fmaxf(fmaf(v.x, a4.x, b4.x), 0.f) : 0.f;
                float v1 = inb ? fmaxf(fmaf(v.y, a4.y, b4.y), 0.f) : 0.f;
                float v2 = inb ? fmaxf(fmaf(v.z, a4.z, b4.z), 0.f) : 0.f;
                float v3 = inb ? fmaxf(fmaf(v.w, a4.w, b4.w), 0.f) : 0.f;
                split_store(p, v0, v1, v2, v3);
            }
        }
    };

    // ---- stage, interior fast path: no bounds checks ----
    auto stage_fast = [&](int chunk) {
        float4 a4 = *(const float4*)&ab[chunk * 32 + c0];
        float4 b4 = *(const float4*)&ab[64 + chunk * 32 + c0];
        const float* hbase = hin
            + ((size_t)(b * NPIX + (by * 8 - 1) * W_ + (bx * 16 - 1))) * 64
            + chunk * 32 + c0;
        #pragma unroll
        for (int k = 0; k < 6; ++k) {
            int p = k * 32 + pr0;
            if (p < 180) {
                int y = p / 18, xx = p - y * 18;
                float4 v = *(const float4*)(hbase + ((size_t)(y * W_ + xx)) * 64);
                float v0 = fmaxf(fmaf(v.x, a4.x, b4.x), 0.f);
                float v1 = fmaxf(fmaf(v.y, a4.y, b4.y), 0.f);
                float v2 = fmaxf(fmaf(v.z, a4.z, b4.z), 0.f);
                float v3 = fmaxf(fmaf(v.w, a4.w, b4.w), 0.f);
                split_store(p, v0, v1, v2, v3);
            }
        }
    };

    bool interior = (bx >= 1 && bx <= 14 && by >= 1 && by <= 30);

    // ---- compute: 9 taps x 2 k16-slices x (2 octiles x 3 terms) ----
    auto compute_chunk = [&](int chunk) {
        __builtin_amdgcn_s_setprio(1);
        #pragma unroll
        for (int t = 0; t < 9; ++t) {
            int dr = t / 3, dc = t - dr * 3;
            int pbase = (2 * wv + ((lane & 31) >> 4) + dr) * 18 + (lane & 15) + dc;
            #pragma unroll
            for (int s16 = 0; s16 < 2; ++s16) {
                int ss = t * 4 + chunk * 2 + s16;
                const short* wb = g_wpk + ((size_t)((l * 36 + ss) * 2) * 64 + lane) * 16;
                bf16x8 a0h = *(const bf16x8*)(wb);
                bf16x8 a0l = *(const bf16x8*)(wb + 8);
                bf16x8 a1h = *(const bf16x8*)(wb + 1024);
                bf16x8 a1l = *(const bf16x8*)(wb + 1024 + 8);
                int woff = pbase * PS + s16 * 8 + (lane >> 5) * 4;
                bf16x8 bh = *(const bf16x8*)&s_hi[woff];
                bf16x8 bl = *(const bf16x8*)&s_lo[woff];
                acc2[0] = __builtin_amdgcn_mfma_f32_32x32x16_bf16(a0h, bh, acc2[0], 0, 0, 0);
                acc2[0] = __builtin_amdgcn_mfma_f32_32x32x16_bf16(a0h, bl, acc2[0], 0, 0, 0);
                acc2[0] = __builtin_amdgcn_mfma_f32_32x32x16_bf16(a0l, bh, acc2[0], 0, 0, 0);
                acc2[1] = __builtin_amdgcn_mfma_f32_32x32x16_bf16(a1h, bh, acc2[1], 0, 0, 0);
                acc2[1] = __builtin_amdgcn_mfma_f32_32x32x16_bf16(a1h, bl, acc2[1], 0, 0, 0);
                acc2[1] = __builtin_amdgcn_mfma_f32_32x32x16_bf16(a1l, bh, acc2[1], 0, 0, 0);
            }
        }
        __builtin_amdgcn_s_setprio(0);
    };

    // de-phase co-resident blocks (bid +- 256): opposite chunk order
    int ck0 = (bid >> 8) & 1;
    if (interior) stage_fast(ck0); else stage_safe(ck0);
    bar_lds();
    compute_chunk(ck0);
    bar_lds();          // all first-chunk reads done before overwrite
    if (interior) stage_fast(ck0 ^ 1); else stage_safe(ck0 ^ 1);
    bar_lds();
    compute_chunk(ck0 ^ 1);

    // ---- epilogue: ReLU, NHWC stores, BN partials (no global atomics) ----
    // C layout (32x32, guide-verified): col(px) = lane&31,
    // row(oc) = (reg&3) + 8*(reg>>2) + 4*(lane>>5); regs 4a..4a+3 -> 4
    // consecutive oc at base mt*32 + 8a + 4*(lane>>5).
    bar_lds();                    // all reads done; reuse s_hi as s_red
    float* s_red = (float*)s_hi;  // [wv][oc][2] = 2 KB

    int colp = lane & 31;
    int gy = by * 8 + 2 * wv + (colp >> 4);
    int gx = bx * 16 + (colp & 15);
    float* op = hout + ((size_t)(b * NPIX + gy * W_ + gx)) * 64;
    int hi4 = (lane >> 5) * 4;

    #pragma unroll
    for (int mt = 0; mt < 2; ++mt) {
        #pragma unroll
        for (int a = 0; a < 4; ++a) {
            float v0 = fmaxf(acc2[mt][4*a + 0], 0.f);
            float v1 = fmaxf(acc2[mt][4*a + 1], 0.f);
            float v2 = fmaxf(acc2[mt][4*a + 2], 0.f);
            float v3 = fmaxf(acc2[mt][4*a + 3], 0.f);
            int oc0 = mt * 32 + 8 * a + hi4;
            *reinterpret_cast<float4*>(op + oc0) = make_float4(v0, v1, v2, v3);
            // per-oc partial sums over the 32 px (lanes with same hi bit)
            #pragma unroll
            for (int rr = 0; rr < 4; ++rr) {
                float s = (rr == 0) ? v0 : (rr == 1) ? v1 : (rr == 2) ? v2 : v3;
                float qq = s * s;
                #pragma unroll
                for (int off = 1; off < 32; off <<= 1) {
                    s  += __shfl_xor(s,  off);
                    qq += __shfl_xor(qq, off);
                }
                if (colp == 0) {
                    s_red[(wv * 64 + oc0 + rr) * 2]     = s;
                    s_red[(wv * 64 + oc0 + rr) * 2 + 1] = qq;
                }
            }
        }
    }
    __syncthreads();
    if (tid < 128) {
        float v = s_red[tid] + s_red[128 + tid] + s_red[256 + tid] + s_red[384 + tid];
        g_part[(size_t)tid * NBLK + bid] = v;
    }
}

// ---------------------------------------------------------------------------
// BN finalize: tree-reduce NBLK per-block partials per (channel,stat)
// ---------------------------------------------------------------------------
__global__ __launch_bounds__(256) void bn_finalize_kernel(
    const float* __restrict__ gamma, const float* __restrict__ beta)
{
    __shared__ float s[8];
    int c = blockIdx.x;
    int t = threadIdx.x;
    const float* p1 = g_part + (size_t)(2 * c) * NBLK;
    const float* p2 = g_part + (size_t)(2 * c + 1) * NBLK;
    float s1 = 0.f, s2 = 0.f;
    for (int i = t; i < NBLK; i += 256) { s1 += p1[i]; s2 += p2[i]; }
    #pragma unroll
    for (int off = 32; off >= 1; off >>= 1) {
        s1 += __shfl_xor(s1, off);
        s2 += __shfl_xor(s2, off);
    }
    int lane = t & 63, w = t >> 6;
    if (lane == 0) { s[w * 2] = s1; s[w * 2 + 1] = s2; }
    __syncthreads();
    if (t == 0) {
        float sum = s[0] + s[2] + s[4] + s[6];
        float sq  = s[1] + s[3] + s[5] + s[7];
        const float invN = 1.0f / (float)NIMG;
        float mean = sum * invN;
        float var  = sq * invN - mean * mean;
        float a = gamma[c] / sqrtf(var + 1e-5f);
        g_stats[128 + c] = a;
        g_stats[192 + c] = beta[c] - mean * a;
    }
}

// ---------------------------------------------------------------------------
// final conv: NHWC in, 64 -> 1 with pre-op relu(a*x+b); out = xpre - noise
// tile 16x16 px; 2 chunks of 32 ch; LDS act fp32 [324][36]
// ---------------------------------------------------------------------------
__global__ __launch_bounds__(256) void conv_final_kernel(
    const float* __restrict__ hin, const float* __restrict__ wf,
    const float* __restrict__ x, float* __restrict__ out)
{
    __shared__ float s_in[324 * 36];   // 46656 B
    __shared__ float s_bl[20][21];
    __shared__ float s_w[64 * 12];
    int bx = blockIdx.x, by = blockIdx.y, b = blockIdx.z;
    int tid = threadIdx.x;
    const float* xb = x + b * NPIX;
    const float* ab = &g_stats[128];

    for (int i = tid; i < 20*20; i += 256) {
        int r = i / 20, c = i - r * 20;
        int gy = refl(by * 16 + r - 2), gx = refl(bx * 16 + c - 2);
        s_bl[r][c] = prep1(xb[gy * W_ + gx]);
    }
    for (int i = tid; i < 576; i += 256) {
        int ic = i / 9, t = i - ic * 9;
        s_w[ic * 12 + t] = wf[i];
    }
    __syncthreads();

    int px = tid & 15, py = tid >> 4;
    float ctr = s_bl[py + 2][px + 2];
    float num = 0.f, den = 0.f;
    #pragma unroll
    for (int dy = -2; dy <= 2; ++dy)
        #pragma unroll
        for (int dx = -2; dx <= 2; ++dx) {
            float nb = s_bl[py + 2 + dy][px + 2 + dx];
            float d  = nb - ctr;
            float wgt = expf(-(float)(dy*dy + dx*dx) * 2e-4f - d * d * 200.0f);
            num += wgt * nb;
            den += wgt;
        }
    float xpre = num / den;

    int q   = tid & 7;
    int c0  = q * 4;
    int pr0 = tid >> 3;
    float acc = 0.f;

    for (int chunk = 0; chunk < 2; ++chunk) {
        __syncthreads();
        float4 a4 = *(const float4*)&ab[chunk * 32 + c0];
        float4 b4 = *(const float4*)&ab[64 + chunk * 32 + c0];
        #pragma unroll
        for (int k = 0; k < 11; ++k) {
            int p = k * 32 + pr0;
            if (p < 324) {
                int y = p / 18, xx = p - y * 18;
                int gy = by * 16 + y - 1, gx = bx * 16 + xx - 1;
                bool inb = (gy >= 0 && gy < H_ && gx >= 0 && gx < W_);
                const float4* src = (const float4*)(
                    hin + ((size_t)(b * NPIX + (inb ? gy * W_ + gx : 0))) * 64 + chunk * 32 + c0);
                float4 v = *src;
                float4 o;
                o.x = inb ? fmaxf(fmaf(v.x, a4.x, b4.x), 0.f) : 0.f;
                o.y = inb ? fmaxf(fmaf(v.y, a4.y, b4.y), 0.f) : 0.f;
                o.z = inb ? fmaxf(fmaf(v.z, a4.z, b4.z), 0.f) : 0.f;
                o.w = inb ? fmaxf(fmaf(v.w, a4.w, b4.w), 0.f) : 0.f;
                *(float4*)&s_in[p * 36 + 4*q] = o;
            }
        }
        __syncthreads();

        #pragma unroll
        for (int u = 0; u < 8; ++u) {
            f32x4 wreg[4][3];
            #pragma unroll
            for (int e = 0; e < 4; ++e)
                #pragma unroll
                for (int g = 0; g < 3; ++g)
                    wreg[e][g] = *(const f32x4*)&s_w[(chunk * 32 + u * 4 + e) * 12 + g * 4];
            #pragma unroll
            for (int t = 0; t < 9; ++t) {
                int dr = t / 3, dc = t - dr * 3;
                const float4 hv = *(const float4*)&s_in[((py + dr) * 18 + px + dc) * 36 + 4 * u];
                acc = fmaf(hv.x, wreg[0][t >> 2][t & 3], acc);
                acc = fmaf(hv.y, wreg[1][t >> 2][t & 3], acc);
                acc = fmaf(hv.z, wreg[2][t >> 2][t & 3], acc);
                acc = fmaf(hv.w, wreg[3][t >> 2][t & 3], acc);
            }
        }
    }

    int gy = by * 16 + py, gx = bx * 16 + px;
    out[b * NPIX + gy * W_ + gx] = xpre - acc;
}

// ---------------------------------------------------------------------------
// launcher — ws: hA fp32 @0, hB fp32 @134217728 (NHWC layout)
// ---------------------------------------------------------------------------
extern "C" void kernel_launch(void* const* d_in, const int* in_sizes, int n_in,
                              void* d_out, int out_size, void* d_ws, size_t ws_size,
                              hipStream_t stream)
{
    const float* x        = (const float*)d_in[0];
    const float* w_init   = (const float*)d_in[1];
    const float* w_body   = (const float*)d_in[2];
    const float* bn_gamma = (const float*)d_in[3];
    const float* bn_beta  = (const float*)d_in[4];
    const float* w_final  = (const float*)d_in[5];
    float* out = (float*)d_out;

    char* wsb = (char*)d_ws;
    float* hA = (float*)wsb;
    float* hB = (float*)(wsb + 134217728ULL);

    init_ab_kernel <<<1, 64, 0, stream>>>();
    prepack_kernel <<<270, 256, 0, stream>>>(w_body);
    conv_init_kernel<<<dim3(8, 32, 8), 256, 0, stream>>>(x, w_init, hA);

    float* cur = hA;
    float* nxt = hB;
    for (int l = 0; l < 15; ++l) {
        conv_body_mfma<<<NBLK, 256, 0, stream>>>(cur, l, nxt);
        bn_finalize_kernel<<<64, 256, 0, stream>>>(bn_gamma + l * 64, bn_beta + l * 64);
        float* tp = cur; cur = nxt; nxt = tp;
    }
    conv_final_kernel<<<dim3(16, 16, 8), 256, 0, stream>>>(cur, w_final, x, out);
}

// Round 19
// 2538.708 us; speedup vs baseline: 1.0101x; 1.0101x over previous
//
#include <hip/hip_runtime.h>
#include <math.h>

#define B_   8
#define CH   64
#define H_   256
#define W_   256
#define NPIX (H_*W_)        // 65536
#define NIMG (B_*NPIX)      // 524288
#define NBLK 4096           // body-conv blocks (16x8 px tiles)
#define PS   16             // LDS pixel stride in dwords

typedef short bf16x8 __attribute__((ext_vector_type(8)));
typedef float f32x4  __attribute__((ext_vector_type(4)));
typedef float f32x16 __attribute__((ext_vector_type(16)));

// persistent device-side scratch (outside ws; recomputed every launch)
__device__ float g_stats[256];        // [128..191] a, [192..255] b
__device__ float g_part[128 * NBLK];  // per-block BN partials, [slot][block]
// packed A-frags for 32x32x16: [l][36 k16-slices][2 octiles][64 lanes][8hi+8lo]
__device__ __align__(16) short g_wpk[15 * 36 * 2 * 64 * 16];

// ---------------------------------------------------------------------------
// helpers
// ---------------------------------------------------------------------------
__device__ __forceinline__ int refl(int i) {
    if (i < 0)    return -i;
    if (i >= 256) return 510 - i;
    return i;
}
__device__ __forceinline__ float prep1(float v) {
    float xn = fminf(fmaxf((v + 1.0f) * 0.5f, 1e-6f), 1.0f);
    return 0.6f * xn + 0.4f * xn * sqrtf(xn);
}
__device__ __forceinline__ unsigned short bf16_rne(float f) {
    union { float f; unsigned u; } v; v.f = f;
    unsigned r = v.u + 0x7FFFu + ((v.u >> 16) & 1u);
    return (unsigned short)(r >> 16);
}
__device__ __forceinline__ float bf16_f(unsigned short h) {
    union { float f; unsigned u; } v; v.u = ((unsigned)h) << 16;
    return v.f;
}
// pack 2 f32 -> 2 bf16 in one instr (src0 -> low half)
__device__ __forceinline__ unsigned cvt_pk_bf16(float a, float b) {
    unsigned r;
    asm volatile("v_cvt_pk_bf16_f32 %0, %1, %2" : "=v"(r) : "v"(a), "v"(b));
    return r;
}
// barrier that does NOT drain vmcnt; LDS visibility needs only lgkmcnt(0).
__device__ __forceinline__ void bar_lds() {
    asm volatile("s_waitcnt lgkmcnt(0)" ::: "memory");
    __builtin_amdgcn_s_barrier();
}

// ---------------------------------------------------------------------------
// init affine: a=1, b=0
// ---------------------------------------------------------------------------
__global__ void init_ab_kernel() {
    int c = threadIdx.x;            // 64
    g_stats[128 + c] = 1.0f;
    g_stats[192 + c] = 0.0f;
}

// ---------------------------------------------------------------------------
// weight prepack for 32x32x16 A-frags, split bf16 hi/lo.
// k = t*64 + ic; k16-slice ss = t*4 + icq (icq in 0..3).
// A frag (32x32x16): lane: row(oc) = mt*32 + (lane&31), k = (lane>>5)*8 + j
// ---------------------------------------------------------------------------
__global__ void prepack_kernel(const float* __restrict__ w_body) {
    int idx = blockIdx.x * 256 + threadIdx.x;
    if (idx >= 15*36*2*64) return;
    int lane = idx & 63;
    int mt   = (idx >> 6) & 1;
    int r2   = idx >> 7;            // l*36 + ss
    int l    = r2 / 36;
    int ss   = r2 - l * 36;
    int t   = ss >> 2;
    int icq = ss & 3;
    int oc  = mt * 32 + (lane & 31);
    int icb = icq * 16 + (lane >> 5) * 8;
    union { short s[8]; int4 v; } uh, ul;
    #pragma unroll
    for (int j = 0; j < 8; ++j) {
        float w = w_body[(((size_t)l * 64 + oc) * 64 + (icb + j)) * 9 + t];
        unsigned short h = bf16_rne(w);
        unsigned short lo = bf16_rne(w - bf16_f(h));
        uh.s[j] = (short)h;
        ul.s[j] = (short)lo;
    }
    int4* dst = (int4*)(g_wpk + (size_t)idx * 16);
    dst[0] = uh.v;
    dst[1] = ul.v;
}

// ---------------------------------------------------------------------------
// init conv: xpre (prep+bilateral inline) -> 1->64ch 3x3 SAME, ReLU
// output NHWC: h[(b*NPIX + y*W + x)*64 + c]
// ---------------------------------------------------------------------------
__global__ __launch_bounds__(256) void conv_init_kernel(
    const float* __restrict__ x, const float* __restrict__ wi,
    float* __restrict__ h)
{
    __shared__ float s_bl[14][38];
    __shared__ float s_xp[10][34];
    __shared__ float s_w[64 * 12];    // padded rows of 12 for aligned b128
    int bx = blockIdx.x, by = blockIdx.y, b = blockIdx.z;
    int tid = threadIdx.x;
    const float* xb = x + b * NPIX;

    for (int i = tid; i < 14*38; i += 256) {
        int r = i / 38, c = i - r * 38;
        int gy = refl(by * 8 + r - 3), gx = refl(bx * 32 + c - 3);
        s_bl[r][c] = prep1(xb[gy * W_ + gx]);
    }
    for (int i = tid; i < 576; i += 256) {
        int oc = i / 9, t = i - oc * 9;
        s_w[oc * 12 + t] = wi[i];
    }
    __syncthreads();

    for (int i = tid; i < 10*34; i += 256) {
        int r = i / 34, c = i - r * 34;
        int gy = by * 8 + r - 1, gx = bx * 32 + c - 1;
        float v = 0.f;
        if (gy >= 0 && gy < H_ && gx >= 0 && gx < W_) {
            float ctr = s_bl[r + 2][c + 2];
            float num = 0.f, den = 0.f;
            #pragma unroll
            for (int dy = -2; dy <= 2; ++dy)
                #pragma unroll
                for (int dx = -2; dx <= 2; ++dx) {
                    float nb = s_bl[r + 2 + dy][c + 2 + dx];
                    float d  = nb - ctr;
                    float wgt = expf(-(float)(dy*dy + dx*dx) * 2e-4f - d * d * 200.0f);
                    num += wgt * nb;
                    den += wgt;
                }
            v = num / den;
        }
        s_xp[r][c] = v;
    }
    __syncthreads();

    int px = tid & 31, py = tid >> 5;
    float v[9];
    #pragma unroll
    for (int dr = 0; dr < 3; ++dr)
        #pragma unroll
        for (int dc = 0; dc < 3; ++dc)
            v[dr*3+dc] = s_xp[py + dr][px + dc];

    float acc[64];
    #pragma unroll
    for (int oc = 0; oc < 64; ++oc) {
        f32x4 w0 = *(const f32x4*)&s_w[oc * 12];
        f32x4 w1 = *(const f32x4*)&s_w[oc * 12 + 4];
        float w8 = s_w[oc * 12 + 8];
        float a = w0[0]*v[0] + w0[1]*v[1] + w0[2]*v[2] + w0[3]*v[3];
        a += w1[0]*v[4] + w1[1]*v[5] + w1[2]*v[6] + w1[3]*v[7];
        a = fmaf(w8, v[8], a);
        acc[oc] = fmaxf(a, 0.f);
    }

    int gy = by * 8 + py, gx = bx * 32 + px;
    float* outp = h + ((size_t)(b * NPIX + gy * W_ + gx)) * 64;
    #pragma unroll
    for (int c4 = 0; c4 < 16; ++c4) {
        float4 o = make_float4(acc[4*c4], acc[4*c4+1], acc[4*c4+2], acc[4*c4+3]);
        *reinterpret_cast<float4*>(outp + 4*c4) = o;
    }
}

// ---------------------------------------------------------------------------
// body conv via 32x32x16 MFMA implicit GEMM, split-bf16 (3-term), NHWC.
// block: 16x8 px x 64 oc; wave wv: px rows {2wv, 2wv+1} x 64 oc.
// LDS: [p][16 dwords] with pixel-indexed XOR swizzle col^=((p>>1)&3)<<2 —
// spreads same-parity pixels across column quads; b128 reads conflict-free
// (R18's 14.2M conflicts were the 2-column read pattern at stride 16).
// ---------------------------------------------------------------------------
__global__ __launch_bounds__(256, 4) void conv_body_mfma(
    const float* __restrict__ hin, int l, float* __restrict__ hout)
{
    __shared__ unsigned s_hi[180 * PS];   // 11520 B (reused as s_red at end)
    __shared__ unsigned s_lo[180 * PS];   // 11520 B

    int tid  = threadIdx.x;
    int lane = tid & 63;
    int wv   = tid >> 6;

    // XCD swizzle: 4096 blocks / 8 XCDs -> one image per XCD
    int bid = blockIdx.x;
    int swz = (bid & 7) * 512 + (bid >> 3);
    int bx = swz & 15;            // 16 x-tiles of 16
    int by = (swz >> 4) & 31;     // 32 y-tiles of 8
    int b  = swz >> 9;            // 8 images

    const float* ab = &g_stats[128];
    int q   = tid & 7;          // channel quad (fixed per thread)
    int c0  = q * 4;            // ch offset within 32-ch chunk
    int pr0 = tid >> 3;         // pixel base for staging (0..31)

    f32x16 acc2[2];
    acc2[0] = (f32x16){0.f,0.f,0.f,0.f,0.f,0.f,0.f,0.f,0.f,0.f,0.f,0.f,0.f,0.f,0.f,0.f};
    acc2[1] = acc2[0];

    // split 4 fp32 -> hi/lo bf16 pairs, store to LDS with pixel XOR swizzle
    auto split_store = [&](int p, float v0, float v1, float v2, float v3) {
        int swc = ((p >> 1) & 3) << 2;
        unsigned hh0 = cvt_pk_bf16(v0, v1);
        unsigned hh1 = cvt_pk_bf16(v2, v3);
        float f0 = __uint_as_float(hh0 << 16);
        float f1 = __uint_as_float(hh0 & 0xffff0000u);
        float f2 = __uint_as_float(hh1 << 16);
        float f3 = __uint_as_float(hh1 & 0xffff0000u);
        unsigned ll0 = cvt_pk_bf16(v0 - f0, v1 - f1);
        unsigned ll1 = cvt_pk_bf16(v2 - f2, v3 - f3);
        int col = (2 * q) ^ swc;
        *(uint2*)&s_hi[p * PS + col] = make_uint2(hh0, hh1);
        *(uint2*)&s_lo[p * PS + col] = make_uint2(ll0, ll1);
    };

    // ---- stage a 32-ch chunk (edge-safe path) ----
    auto stage_safe = [&](int chunk) {
        float4 a4 = *(const float4*)&ab[chunk * 32 + c0];
        float4 b4 = *(const float4*)&ab[64 + chunk * 32 + c0];
        #pragma unroll
        for (int k = 0; k < 6; ++k) {
            int p = k * 32 + pr0;
            if (p < 180) {
                int y = p / 18, xx = p - y * 18;
                int gy = by * 8 + y - 1, gx = bx * 16 + xx - 1;
                bool inb = (gy >= 0 && gy < H_ && gx >= 0 && gx < W_);
                const float4* src = (const float4*)(
                    hin + ((size_t)(b * NPIX + (inb ? gy * W_ + gx : 0))) * 64 + chunk * 32 + c0);
                float4 v = *src;
                float v0 = inb ? fmaxf(fmaf(v.x, a4.x, b4.x), 0.f) : 0.f;
                float v1 = inb ? fmaxf(fmaf(v.y, a4.y, b4.y), 0.f) : 0.f;
                float v2 = inb ? fmaxf(fmaf(v.z, a4.z, b4.z), 0.f) : 0.f;
                float v3 = inb ? fmaxf(fmaf(v.w, a4.w, b4.w), 0.f) : 0.f;
                split_store(p, v0, v1, v2, v3);
            }
        }
    };

    // ---- stage, interior fast path: no bounds checks ----
    auto stage_fast = [&](int chunk) {
        float4 a4 = *(const float4*)&ab[chunk * 32 + c0];
        float4 b4 = *(const float4*)&ab[64 + chunk * 32 + c0];
        const float* hbase = hin
            + ((size_t)(b * NPIX + (by * 8 - 1) * W_ + (bx * 16 - 1))) * 64
            + chunk * 32 + c0;
        #pragma unroll
        for (int k = 0; k < 6; ++k) {
            int p = k * 32 + pr0;
            if (p < 180) {
                int y = p / 18, xx = p - y * 18;
                float4 v = *(const float4*)(hbase + ((size_t)(y * W_ + xx)) * 64);
                float v0 = fmaxf(fmaf(v.x, a4.x, b4.x), 0.f);
                float v1 = fmaxf(fmaf(v.y, a4.y, b4.y), 0.f);
                float v2 = fmaxf(fmaf(v.z, a4.z, b4.z), 0.f);
                float v3 = fmaxf(fmaf(v.w, a4.w, b4.w), 0.f);
                split_store(p, v0, v1, v2, v3);
            }
        }
    };

    bool interior = (bx >= 1 && bx <= 14 && by >= 1 && by <= 30);

    // ---- compute: 9 taps x 2 k16-slices x (2 octiles x 3 terms) ----
    auto compute_chunk = [&](int chunk) {
        __builtin_amdgcn_s_setprio(1);
        #pragma unroll
        for (int t = 0; t < 9; ++t) {
            int dr = t / 3, dc = t - dr * 3;
            int pb = (2 * wv + ((lane & 31) >> 4) + dr) * 18 + (lane & 15) + dc;
            int swc = ((pb >> 1) & 3) << 2;
            #pragma unroll
            for (int s16 = 0; s16 < 2; ++s16) {
                int ss = t * 4 + chunk * 2 + s16;
                const short* wb = g_wpk + ((size_t)((l * 36 + ss) * 2) * 64 + lane) * 16;
                bf16x8 a0h = *(const bf16x8*)(wb);
                bf16x8 a0l = *(const bf16x8*)(wb + 8);
                bf16x8 a1h = *(const bf16x8*)(wb + 1024);
                bf16x8 a1l = *(const bf16x8*)(wb + 1024 + 8);
                int col = (s16 * 8 + (lane >> 5) * 4) ^ swc;
                int woff = pb * PS + col;
                bf16x8 bh = *(const bf16x8*)&s_hi[woff];
                bf16x8 bl = *(const bf16x8*)&s_lo[woff];
                acc2[0] = __builtin_amdgcn_mfma_f32_32x32x16_bf16(a0h, bh, acc2[0], 0, 0, 0);
                acc2[0] = __builtin_amdgcn_mfma_f32_32x32x16_bf16(a0h, bl, acc2[0], 0, 0, 0);
                acc2[0] = __builtin_amdgcn_mfma_f32_32x32x16_bf16(a0l, bh, acc2[0], 0, 0, 0);
                acc2[1] = __builtin_amdgcn_mfma_f32_32x32x16_bf16(a1h, bh, acc2[1], 0, 0, 0);
                acc2[1] = __builtin_amdgcn_mfma_f32_32x32x16_bf16(a1h, bl, acc2[1], 0, 0, 0);
                acc2[1] = __builtin_amdgcn_mfma_f32_32x32x16_bf16(a1l, bh, acc2[1], 0, 0, 0);
            }
        }
        __builtin_amdgcn_s_setprio(0);
    };

    // de-phase co-resident blocks (bid +- 256): opposite chunk order
    int ck0 = (bid >> 8) & 1;
    if (interior) stage_fast(ck0); else stage_safe(ck0);
    bar_lds();
    compute_chunk(ck0);
    bar_lds();          // all first-chunk reads done before overwrite
    if (interior) stage_fast(ck0 ^ 1); else stage_safe(ck0 ^ 1);
    bar_lds();
    compute_chunk(ck0 ^ 1);

    // ---- epilogue: ReLU, NHWC stores, BN partials (no global atomics) ----
    // C layout (32x32, guide-verified): col(px) = lane&31,
    // row(oc) = (reg&3) + 8*(reg>>2) + 4*(lane>>5).
    bar_lds();                    // all reads done; reuse s_hi as s_red
    float* s_red = (float*)s_hi;  // [wv][oc][2] = 2 KB

    int colp = lane & 31;
    int gy = by * 8 + 2 * wv + (colp >> 4);
    int gx = bx * 16 + (colp & 15);
    float* op = hout + ((size_t)(b * NPIX + gy * W_ + gx)) * 64;
    int hi4 = (lane >> 5) * 4;

    #pragma unroll
    for (int mt = 0; mt < 2; ++mt) {
        #pragma unroll
        for (int a = 0; a < 4; ++a) {
            float v0 = fmaxf(acc2[mt][4*a + 0], 0.f);
            float v1 = fmaxf(acc2[mt][4*a + 1], 0.f);
            float v2 = fmaxf(acc2[mt][4*a + 2], 0.f);
            float v3 = fmaxf(acc2[mt][4*a + 3], 0.f);
            int oc0 = mt * 32 + 8 * a + hi4;
            *reinterpret_cast<float4*>(op + oc0) = make_float4(v0, v1, v2, v3);
            #pragma unroll
            for (int rr = 0; rr < 4; ++rr) {
                float s = (rr == 0) ? v0 : (rr == 1) ? v1 : (rr == 2) ? v2 : v3;
                float qq = s * s;
                #pragma unroll
                for (int off = 1; off < 32; off <<= 1) {
                    s  += __shfl_xor(s,  off);
                    qq += __shfl_xor(qq, off);
                }
                if (colp == 0) {
                    s_red[(wv * 64 + oc0 + rr) * 2]     = s;
                    s_red[(wv * 64 + oc0 + rr) * 2 + 1] = qq;
                }
            }
        }
    }
    __syncthreads();
    if (tid < 128) {
        float v = s_red[tid] + s_red[128 + tid] + s_red[256 + tid] + s_red[384 + tid];
        g_part[(size_t)tid * NBLK + bid] = v;
    }
}

// ---------------------------------------------------------------------------
// BN finalize: tree-reduce NBLK per-block partials per (channel,stat)
// ---------------------------------------------------------------------------
__global__ __launch_bounds__(256) void bn_finalize_kernel(
    const float* __restrict__ gamma, const float* __restrict__ beta)
{
    __shared__ float s[8];
    int c = blockIdx.x;
    int t = threadIdx.x;
    const float* p1 = g_part + (size_t)(2 * c) * NBLK;
    const float* p2 = g_part + (size_t)(2 * c + 1) * NBLK;
    float s1 = 0.f, s2 = 0.f;
    for (int i = t; i < NBLK; i += 256) { s1 += p1[i]; s2 += p2[i]; }
    #pragma unroll
    for (int off = 32; off >= 1; off >>= 1) {
        s1 += __shfl_xor(s1, off);
        s2 += __shfl_xor(s2, off);
    }
    int lane = t & 63, w = t >> 6;
    if (lane == 0) { s[w * 2] = s1; s[w * 2 + 1] = s2; }
    __syncthreads();
    if (t == 0) {
        float sum = s[0] + s[2] + s[4] + s[6];
        float sq  = s[1] + s[3] + s[5] + s[7];
        const float invN = 1.0f / (float)NIMG;
        float mean = sum * invN;
        float var  = sq * invN - mean * mean;
        float a = gamma[c] / sqrtf(var + 1e-5f);
        g_stats[128 + c] = a;
        g_stats[192 + c] = beta[c] - mean * a;
    }
}

// ---------------------------------------------------------------------------
// final conv: NHWC in, 64 -> 1 with pre-op relu(a*x+b); out = xpre - noise
// tile 16x16 px; 2 chunks of 32 ch; LDS act fp32 [324][36]
// ---------------------------------------------------------------------------
__global__ __launch_bounds__(256) void conv_final_kernel(
    const float* __restrict__ hin, const float* __restrict__ wf,
    const float* __restrict__ x, float* __restrict__ out)
{
    __shared__ float s_in[324 * 36];   // 46656 B
    __shared__ float s_bl[20][21];
    __shared__ float s_w[64 * 12];
    int bx = blockIdx.x, by = blockIdx.y, b = blockIdx.z;
    int tid = threadIdx.x;
    const float* xb = x + b * NPIX;
    const float* ab = &g_stats[128];

    for (int i = tid; i < 20*20; i += 256) {
        int r = i / 20, c = i - r * 20;
        int gy = refl(by * 16 + r - 2), gx = refl(bx * 16 + c - 2);
        s_bl[r][c] = prep1(xb[gy * W_ + gx]);
    }
    for (int i = tid; i < 576; i += 256) {
        int ic = i / 9, t = i - ic * 9;
        s_w[ic * 12 + t] = wf[i];
    }
    __syncthreads();

    int px = tid & 15, py = tid >> 4;
    float ctr = s_bl[py + 2][px + 2];
    float num = 0.f, den = 0.f;
    #pragma unroll
    for (int dy = -2; dy <= 2; ++dy)
        #pragma unroll
        for (int dx = -2; dx <= 2; ++dx) {
            float nb = s_bl[py + 2 + dy][px + 2 + dx];
            float d  = nb - ctr;
            float wgt = expf(-(float)(dy*dy + dx*dx) * 2e-4f - d * d * 200.0f);
            num += wgt * nb;
            den += wgt;
        }
    float xpre = num / den;

    int q   = tid & 7;
    int c0  = q * 4;
    int pr0 = tid >> 3;
    float acc = 0.f;

    for (int chunk = 0; chunk < 2; ++chunk) {
        __syncthreads();
        float4 a4 = *(const float4*)&ab[chunk * 32 + c0];
        float4 b4 = *(const float4*)&ab[64 + chunk * 32 + c0];
        #pragma unroll
        for (int k = 0; k < 11; ++k) {
            int p = k * 32 + pr0;
            if (p < 324) {
                int y = p / 18, xx = p - y * 18;
                int gy = by * 16 + y - 1, gx = bx * 16 + xx - 1;
                bool inb = (gy >= 0 && gy < H_ && gx >= 0 && gx < W_);
                const float4* src = (const float4*)(
                    hin + ((size_t)(b * NPIX + (inb ? gy * W_ + gx : 0))) * 64 + chunk * 32 + c0);
                float4 v = *src;
                float4 o;
                o.x = inb ? fmaxf(fmaf(v.x, a4.x, b4.x), 0.f) : 0.f;
                o.y = inb ? fmaxf(fmaf(v.y, a4.y, b4.y), 0.f) : 0.f;
                o.z = inb ? fmaxf(fmaf(v.z, a4.z, b4.z), 0.f) : 0.f;
                o.w = inb ? fmaxf(fmaf(v.w, a4.w, b4.w), 0.f) : 0.f;
                *(float4*)&s_in[p * 36 + 4*q] = o;
            }
        }
        __syncthreads();

        #pragma unroll
        for (int u = 0; u < 8; ++u) {
            f32x4 wreg[4][3];
            #pragma unroll
            for (int e = 0; e < 4; ++e)
                #pragma unroll
                for (int g = 0; g < 3; ++g)
                    wreg[e][g] = *(const f32x4*)&s_w[(chunk * 32 + u * 4 + e) * 12 + g * 4];
            #pragma unroll
            for (int t = 0; t < 9; ++t) {
                int dr = t / 3, dc = t - dr * 3;
                const float4 hv = *(const float4*)&s_in[((py + dr) * 18 + px + dc) * 36 + 4 * u];
                acc = fmaf(hv.x, wreg[0][t >> 2][t & 3], acc);
                acc = fmaf(hv.y, wreg[1][t >> 2][t & 3], acc);
                acc = fmaf(hv.z, wreg[2][t >> 2][t & 3], acc);
                acc = fmaf(hv.w, wreg[3][t >> 2][t & 3], acc);
            }
        }
    }

    int gy = by * 16 + py, gx = bx * 16 + px;
    out[b * NPIX + gy * W_ + gx] = xpre - acc;
}

// ---------------------------------------------------------------------------
// launcher — ws: hA fp32 @0, hB fp32 @134217728 (NHWC layout)
// ---------------------------------------------------------------------------
extern "C" void kernel_launch(void* const* d_in, const int* in_sizes, int n_in,
                              void* d_out, int out_size, void* d_ws, size_t ws_size,
                              hipStream_t stream)
{
    const float* x        = (const float*)d_in[0];
    const float* w_init   = (const float*)d_in[1];
    const float* w_body   = (const float*)d_in[2];
    const float* bn_gamma = (const float*)d_in[3];
    const float* bn_beta  = (const float*)d_in[4];
    const float* w_final  = (const float*)d_in[5];
    float* out = (float*)d_out;

    char* wsb = (char*)d_ws;
    float* hA = (float*)wsb;
    float* hB = (float*)(wsb + 134217728ULL);

    init_ab_kernel <<<1, 64, 0, stream>>>();
    prepack_kernel <<<270, 256, 0, stream>>>(w_body);
    conv_init_kernel<<<dim3(8, 32, 8), 256, 0, stream>>>(x, w_init, hA);

    float* cur = hA;
    float* nxt = hB;
    for (int l = 0; l < 15; ++l) {
        conv_body_mfma<<<NBLK, 256, 0, stream>>>(cur, l, nxt);
        bn_finalize_kernel<<<64, 256, 0, stream>>>(bn_gamma + l * 64, bn_beta + l * 64);
        float* tp = cur; cur = nxt; nxt = tp;
    }
    conv_final_kernel<<<dim3(16, 16, 8), 256, 0, stream>>>(cur, w_final, x, out);
}

// Round 20
// 2138.930 us; speedup vs baseline: 1.1989x; 1.1869x over previous
//
#include <hip/hip_runtime.h>
#include <math.h>

#define B_   8
#define CH   64
#define H_   256
#define W_   256
#define NPIX (H_*W_)        // 65536
#define NIMG (B_*NPIX)      // 524288
#define NBLK 4096           // body-conv blocks (16x8 px tiles)
#define PS   16             // LDS pixel stride in dwords (uniform bank spread)

typedef short bf16x8 __attribute__((ext_vector_type(8)));
typedef float f32x4  __attribute__((ext_vector_type(4)));

// persistent device-side scratch (outside ws; recomputed every launch)
__device__ float g_stats[256];        // [128..191] a, [192..255] b
__device__ float g_part[128 * NBLK];  // per-block BN partials, [slot][block]
__device__ __align__(16) short g_wpk[15 * 18 * 4 * 64 * 16];  // packed A-frags hi/lo

// ---------------------------------------------------------------------------
// helpers
// ---------------------------------------------------------------------------
__device__ __forceinline__ int refl(int i) {
    if (i < 0)    return -i;
    if (i >= 256) return 510 - i;
    return i;
}
__device__ __forceinline__ float prep1(float v) {
    float xn = fminf(fmaxf((v + 1.0f) * 0.5f, 1e-6f), 1.0f);
    return 0.6f * xn + 0.4f * xn * sqrtf(xn);
}
__device__ __forceinline__ unsigned short bf16_rne(float f) {
    union { float f; unsigned u; } v; v.f = f;
    unsigned r = v.u + 0x7FFFu + ((v.u >> 16) & 1u);
    return (unsigned short)(r >> 16);
}
__device__ __forceinline__ float bf16_f(unsigned short h) {
    union { float f; unsigned u; } v; v.u = ((unsigned)h) << 16;
    return v.f;
}
// pack 2 f32 -> 2 bf16 in one instr (src0 -> low half)
__device__ __forceinline__ unsigned cvt_pk_bf16(float a, float b) {
    unsigned r;
    asm volatile("v_cvt_pk_bf16_f32 %0, %1, %2" : "=v"(r) : "v"(a), "v"(b));
    return r;
}
// barrier that does NOT drain vmcnt; LDS visibility needs only lgkmcnt(0).
__device__ __forceinline__ void bar_lds() {
    asm volatile("s_waitcnt lgkmcnt(0)" ::: "memory");
    __builtin_amdgcn_s_barrier();
}

// ---------------------------------------------------------------------------
// init affine: a=1, b=0
// ---------------------------------------------------------------------------
__global__ void init_ab_kernel() {
    int c = threadIdx.x;            // 64
    g_stats[128 + c] = 1.0f;
    g_stats[192 + c] = 0.0f;
}

// ---------------------------------------------------------------------------
// weight prepack: w_body[l][oc][ic][3][3] -> A-fragment order, split bf16 hi/lo
// k = t*64 + ic; slice s (32 k): t = s>>1, ic_half = s&1.
// A frag (16x16x32): lane: row(oc)=lane&15, k=(lane>>4)*8+j
// ---------------------------------------------------------------------------
__global__ void prepack_kernel(const float* __restrict__ w_body) {
    int idx = blockIdx.x * 256 + threadIdx.x;
    if (idx >= 15*18*4*64) return;
    int lane = idx & 63;
    int m    = (idx >> 6) & 3;
    int r2   = idx >> 8;            // l*18 + s
    int l    = r2 / 18;
    int s    = r2 - l * 18;
    int t  = s >> 1;
    int oc = m * 16 + (lane & 15);
    int icb = (s & 1) * 32 + (lane >> 4) * 8;
    union { short s[8]; int4 v; } uh, ul;
    #pragma unroll
    for (int j = 0; j < 8; ++j) {
        float w = w_body[(((size_t)l * 64 + oc) * 64 + (icb + j)) * 9 + t];
        unsigned short h = bf16_rne(w);
        unsigned short lo = bf16_rne(w - bf16_f(h));
        uh.s[j] = (short)h;
        ul.s[j] = (short)lo;
    }
    int4* dst = (int4*)(g_wpk + (size_t)idx * 16);
    dst[0] = uh.v;
    dst[1] = ul.v;
}

// ---------------------------------------------------------------------------
// init conv: xpre (prep+bilateral inline) -> 1->64ch 3x3 SAME, ReLU
// output NHWC: h[(b*NPIX + y*W + x)*64 + c]
// ---------------------------------------------------------------------------
__global__ __launch_bounds__(256) void conv_init_kernel(
    const float* __restrict__ x, const float* __restrict__ wi,
    float* __restrict__ h)
{
    __shared__ float s_bl[14][38];
    __shared__ float s_xp[10][34];
    __shared__ float s_w[64 * 12];    // padded rows of 12 for aligned b128
    int bx = blockIdx.x, by = blockIdx.y, b = blockIdx.z;
    int tid = threadIdx.x;
    const float* xb = x + b * NPIX;

    for (int i = tid; i < 14*38; i += 256) {
        int r = i / 38, c = i - r * 38;
        int gy = refl(by * 8 + r - 3), gx = refl(bx * 32 + c - 3);
        s_bl[r][c] = prep1(xb[gy * W_ + gx]);
    }
    for (int i = tid; i < 576; i += 256) {
        int oc = i / 9, t = i - oc * 9;
        s_w[oc * 12 + t] = wi[i];
    }
    __syncthreads();

    for (int i = tid; i < 10*34; i += 256) {
        int r = i / 34, c = i - r * 34;
        int gy = by * 8 + r - 1, gx = bx * 32 + c - 1;
        float v = 0.f;
        if (gy >= 0 && gy < H_ && gx >= 0 && gx < W_) {
            float ctr = s_bl[r + 2][c + 2];
            float num = 0.f, den = 0.f;
            #pragma unroll
            for (int dy = -2; dy <= 2; ++dy)
                #pragma unroll
                for (int dx = -2; dx <= 2; ++dx) {
                    float nb = s_bl[r + 2 + dy][c + 2 + dx];
                    float d  = nb - ctr;
                    float wgt = expf(-(float)(dy*dy + dx*dx) * 2e-4f - d * d * 200.0f);
                    num += wgt * nb;
                    den += wgt;
                }
            v = num / den;
        }
        s_xp[r][c] = v;
    }
    __syncthreads();

    int px = tid & 31, py = tid >> 5;
    float v[9];
    #pragma unroll
    for (int dr = 0; dr < 3; ++dr)
        #pragma unroll
        for (int dc = 0; dc < 3; ++dc)
            v[dr*3+dc] = s_xp[py + dr][px + dc];

    float acc[64];
    #pragma unroll
    for (int oc = 0; oc < 64; ++oc) {
        f32x4 w0 = *(const f32x4*)&s_w[oc * 12];
        f32x4 w1 = *(const f32x4*)&s_w[oc * 12 + 4];
        float w8 = s_w[oc * 12 + 8];
        float a = w0[0]*v[0] + w0[1]*v[1] + w0[2]*v[2] + w0[3]*v[3];
        a += w1[0]*v[4] + w1[1]*v[5] + w1[2]*v[6] + w1[3]*v[7];
        a = fmaf(w8, v[8], a);
        acc[oc] = fmaxf(a, 0.f);
    }

    int gy = by * 8 + py, gx = bx * 32 + px;
    float* outp = h + ((size_t)(b * NPIX + gy * W_ + gx)) * 64;
    #pragma unroll
    for (int c4 = 0; c4 < 16; ++c4) {
        float4 o = make_float4(acc[4*c4], acc[4*c4+1], acc[4*c4+2], acc[4*c4+3]);
        *reinterpret_cast<float4*>(outp + 4*c4) = o;
    }
}

// ---------------------------------------------------------------------------
// body conv via MFMA implicit GEMM, split-bf16 (3-term), NHWC activations.
// block: 16x8 px x 64 oc; wave wv: px rows {2wv, 2wv+1} x 64 oc
// LDS act layout: [p = y*18+x][16 dwords (32 ch packed 2/dword)], PS=16 ->
// uniform bank spread read (8/bank) & write (4/bank); 23 KB -> 6-block fit.
// launch_bounds (256,4): proven no-spill config (VGPR 64).
// ---------------------------------------------------------------------------
__global__ __launch_bounds__(256, 4) void conv_body_mfma(
    const float* __restrict__ hin, int l, float* __restrict__ hout)
{
    __shared__ unsigned s_hi[180 * PS];   // 11520 B (reused as s_red at end)
    __shared__ unsigned s_lo[180 * PS];   // 11520 B

    int tid  = threadIdx.x;
    int lane = tid & 63;
    int wv   = tid >> 6;

    // XCD swizzle: 4096 blocks / 8 XCDs -> one image per XCD
    int bid = blockIdx.x;
    int swz = (bid & 7) * 512 + (bid >> 3);
    int bx = swz & 15;            // 16 x-tiles of 16
    int by = (swz >> 4) & 31;     // 32 y-tiles of 8
    int b  = swz >> 9;            // 8 images

    const float* ab = &g_stats[128];
    int q   = tid & 7;          // channel quad (fixed per thread)
    int c0  = q * 4;            // ch offset within 32-ch chunk
    int pr0 = tid >> 3;         // pixel base for staging (0..31)

    f32x4 acc[4][2];
    #pragma unroll
    for (int m = 0; m < 4; ++m)
        #pragma unroll
        for (int n = 0; n < 2; ++n)
            acc[m][n] = (f32x4){0.f, 0.f, 0.f, 0.f};

    // split 4 fp32 -> hi/lo bf16 pairs and store to LDS
    auto split_store = [&](int p, float v0, float v1, float v2, float v3) {
        unsigned hh0 = cvt_pk_bf16(v0, v1);
        unsigned hh1 = cvt_pk_bf16(v2, v3);
        float f0 = __uint_as_float(hh0 << 16);
        float f1 = __uint_as_float(hh0 & 0xffff0000u);
        float f2 = __uint_as_float(hh1 << 16);
        float f3 = __uint_as_float(hh1 & 0xffff0000u);
        unsigned ll0 = cvt_pk_bf16(v0 - f0, v1 - f1);
        unsigned ll1 = cvt_pk_bf16(v2 - f2, v3 - f3);
        *(uint2*)&s_hi[p * PS + 2*q] = make_uint2(hh0, hh1);
        *(uint2*)&s_lo[p * PS + 2*q] = make_uint2(ll0, ll1);
    };

    // ---- stage a 32-ch chunk (edge-safe path) ----
    auto stage_safe = [&](int chunk) {
        float4 a4 = *(const float4*)&ab[chunk * 32 + c0];
        float4 b4 = *(const float4*)&ab[64 + chunk * 32 + c0];
        #pragma unroll
        for (int k = 0; k < 6; ++k) {
            int p = k * 32 + pr0;
            if (p < 180) {
                int y = p / 18, xx = p - y * 18;
                int gy = by * 8 + y - 1, gx = bx * 16 + xx - 1;
                bool inb = (gy >= 0 && gy < H_ && gx >= 0 && gx < W_);
                const float4* src = (const float4*)(
                    hin + ((size_t)(b * NPIX + (inb ? gy * W_ + gx : 0))) * 64 + chunk * 32 + c0);
                float4 v = *src;
                float v0 = inb ? fmaxf(fmaf(v.x, a4.x, b4.x), 0.f) : 0.f;
                float v1 = inb ? fmaxf(fmaf(v.y, a4.y, b4.y), 0.f) : 0.f;
                float v2 = inb ? fmaxf(fmaf(v.z, a4.z, b4.z), 0.f) : 0.f;
                float v3 = inb ? fmaxf(fmaf(v.w, a4.w, b4.w), 0.f) : 0.f;
                split_store(p, v0, v1, v2, v3);
            }
        }
    };

    // ---- stage, interior fast path: no bounds checks ----
    auto stage_fast = [&](int chunk) {
        float4 a4 = *(const float4*)&ab[chunk * 32 + c0];
        float4 b4 = *(const float4*)&ab[64 + chunk * 32 + c0];
        const float* hbase = hin
            + ((size_t)(b * NPIX + (by * 8 - 1) * W_ + (bx * 16 - 1))) * 64
            + chunk * 32 + c0;
        #pragma unroll
        for (int k = 0; k < 6; ++k) {
            int p = k * 32 + pr0;
            if (p < 180) {
                int y = p / 18, xx = p - y * 18;
                float4 v = *(const float4*)(hbase + ((size_t)(y * W_ + xx)) * 64);
                float v0 = fmaxf(fmaf(v.x, a4.x, b4.x), 0.f);
                float v1 = fmaxf(fmaf(v.y, a4.y, b4.y), 0.f);
                float v2 = fmaxf(fmaf(v.z, a4.z, b4.z), 0.f);
                float v3 = fmaxf(fmaf(v.w, a4.w, b4.w), 0.f);
                split_store(p, v0, v1, v2, v3);
            }
        }
    };

    bool interior = (bx >= 1 && bx <= 14 && by >= 1 && by <= 30);

    // ---- compute: 9 taps, 3 split terms, n=2 px-rows ----
    auto compute_chunk = [&](int chunk) {
        __builtin_amdgcn_s_setprio(1);
        #pragma unroll
        for (int t = 0; t < 9; ++t) {
            int s = 2 * t + chunk;
            const short* wb = g_wpk + ((size_t)(((l * 18 + s) * 4) * 64 + lane)) * 16;
            bf16x8 a_hi[4], a_lo[4];
            #pragma unroll
            for (int m = 0; m < 4; ++m) {
                const short* pw = wb + (size_t)m * 1024;
                a_hi[m] = *(const bf16x8*)(pw);
                a_lo[m] = *(const bf16x8*)(pw + 8);
            }
            int dr = t / 3, dc = t - dr * 3;
            #pragma unroll
            for (int n = 0; n < 2; ++n) {
                int y = 2 * wv + n + dr;
                int p = y * 18 + dc + (lane & 15);
                int woff = p * PS + (lane >> 4) * 4;
                bf16x8 b_hi = *(const bf16x8*)&s_hi[woff];
                bf16x8 b_lo = *(const bf16x8*)&s_lo[woff];
                #pragma unroll
                for (int m = 0; m < 4; ++m) {
                    acc[m][n] = __builtin_amdgcn_mfma_f32_16x16x32_bf16(a_hi[m], b_hi, acc[m][n], 0, 0, 0);
                    acc[m][n] = __builtin_amdgcn_mfma_f32_16x16x32_bf16(a_hi[m], b_lo, acc[m][n], 0, 0, 0);
                    acc[m][n] = __builtin_amdgcn_mfma_f32_16x16x32_bf16(a_lo[m], b_hi, acc[m][n], 0, 0, 0);
                }
            }
        }
        __builtin_amdgcn_s_setprio(0);
    };

    // de-phase co-resident blocks (bid +- 256): opposite chunk order
    int ck0 = (bid >> 8) & 1;
    if (interior) stage_fast(ck0); else stage_safe(ck0);
    bar_lds();
    compute_chunk(ck0);
    bar_lds();          // all first-chunk reads done before overwrite
    if (interior) stage_fast(ck0 ^ 1); else stage_safe(ck0 ^ 1);
    bar_lds();
    compute_chunk(ck0 ^ 1);

    // ---- epilogue: ReLU, NHWC stores, BN partials (no global atomics) ----
    bar_lds();                    // all reads done; reuse s_hi as s_red
    float* s_red = (float*)s_hi;  // [wv][oc][2] = 2 KB

    int q4  = lane >> 4;
    int gxs = bx * 16 + (lane & 15);
    float ps1[4][4], ps2[4][4];
    #pragma unroll
    for (int m = 0; m < 4; ++m)
        #pragma unroll
        for (int r = 0; r < 4; ++r) { ps1[m][r] = 0.f; ps2[m][r] = 0.f; }

    #pragma unroll
    for (int n = 0; n < 2; ++n) {
        int gy = by * 8 + 2 * wv + n;
        float* op = hout + ((size_t)(b * NPIX + gy * W_ + gxs)) * 64 + q4 * 4;
        #pragma unroll
        for (int m = 0; m < 4; ++m) {
            float a0 = fmaxf(acc[m][n][0], 0.f);
            float a1 = fmaxf(acc[m][n][1], 0.f);
            float a2 = fmaxf(acc[m][n][2], 0.f);
            float a3 = fmaxf(acc[m][n][3], 0.f);
            *reinterpret_cast<float4*>(op + m * 16) = make_float4(a0, a1, a2, a3);
            ps1[m][0] += a0; ps1[m][1] += a1; ps1[m][2] += a2; ps1[m][3] += a3;
            ps2[m][0] += a0*a0; ps2[m][1] += a1*a1; ps2[m][2] += a2*a2; ps2[m][3] += a3*a3;
        }
    }
    #pragma unroll
    for (int m = 0; m < 4; ++m) {
        #pragma unroll
        for (int r = 0; r < 4; ++r) {
            float a = ps1[m][r], s = ps2[m][r];
            #pragma unroll
            for (int off = 1; off < 16; off <<= 1) {
                a += __shfl_xor(a, off);
                s += __shfl_xor(s, off);
            }
            if ((lane & 15) == 0) {
                int oc = m * 16 + q4 * 4 + r;
                s_red[(wv * 64 + oc) * 2]     = a;
                s_red[(wv * 64 + oc) * 2 + 1] = s;
            }
        }
    }
    __syncthreads();
    if (tid < 128) {
        float v = s_red[tid] + s_red[128 + tid] + s_red[256 + tid] + s_red[384 + tid];
        g_part[(size_t)tid * NBLK + bid] = v;
    }
}

// ---------------------------------------------------------------------------
// BN finalize: tree-reduce NBLK per-block partials per (channel,stat)
// ---------------------------------------------------------------------------
__global__ __launch_bounds__(256) void bn_finalize_kernel(
    const float* __restrict__ gamma, const float* __restrict__ beta)
{
    __shared__ float s[8];
    int c = blockIdx.x;
    int t = threadIdx.x;
    const float* p1 = g_part + (size_t)(2 * c) * NBLK;
    const float* p2 = g_part + (size_t)(2 * c + 1) * NBLK;
    float s1 = 0.f, s2 = 0.f;
    for (int i = t; i < NBLK; i += 256) { s1 += p1[i]; s2 += p2[i]; }
    #pragma unroll
    for (int off = 32; off >= 1; off >>= 1) {
        s1 += __shfl_xor(s1, off);
        s2 += __shfl_xor(s2, off);
    }
    int lane = t & 63, w = t >> 6;
    if (lane == 0) { s[w * 2] = s1; s[w * 2 + 1] = s2; }
    __syncthreads();
    if (t == 0) {
        float sum = s[0] + s[2] + s[4] + s[6];
        float sq  = s[1] + s[3] + s[5] + s[7];
        const float invN = 1.0f / (float)NIMG;
        float mean = sum * invN;
        float var  = sq * invN - mean * mean;
        float a = gamma[c] / sqrtf(var + 1e-5f);
        g_stats[128 + c] = a;
        g_stats[192 + c] = beta[c] - mean * a;
    }
}

// ---------------------------------------------------------------------------
// final conv: NHWC in, 64 -> 1 with pre-op relu(a*x+b); out = xpre - noise
// tile 16x16 px; 2 chunks of 32 ch; LDS act fp32 [324][36]
// ---------------------------------------------------------------------------
__global__ __launch_bounds__(256) void conv_final_kernel(
    const float* __restrict__ hin, const float* __restrict__ wf,
    const float* __restrict__ x, float* __restrict__ out)
{
    __shared__ float s_in[324 * 36];   // 46656 B
    __shared__ float s_bl[20][21];
    __shared__ float s_w[64 * 12];
    int bx = blockIdx.x, by = blockIdx.y, b = blockIdx.z;
    int tid = threadIdx.x;
    const float* xb = x + b * NPIX;
    const float* ab = &g_stats[128];

    for (int i = tid; i < 20*20; i += 256) {
        int r = i / 20, c = i - r * 20;
        int gy = refl(by * 16 + r - 2), gx = refl(bx * 16 + c - 2);
        s_bl[r][c] = prep1(xb[gy * W_ + gx]);
    }
    for (int i = tid; i < 576; i += 256) {
        int ic = i / 9, t = i - ic * 9;
        s_w[ic * 12 + t] = wf[i];
    }
    __syncthreads();

    int px = tid & 15, py = tid >> 4;
    float ctr = s_bl[py + 2][px + 2];
    float num = 0.f, den = 0.f;
    #pragma unroll
    for (int dy = -2; dy <= 2; ++dy)
        #pragma unroll
        for (int dx = -2; dx <= 2; ++dx) {
            float nb = s_bl[py + 2 + dy][px + 2 + dx];
            float d  = nb - ctr;
            float wgt = expf(-(float)(dy*dy + dx*dx) * 2e-4f - d * d * 200.0f);
            num += wgt * nb;
            den += wgt;
        }
    float xpre = num / den;

    int q   = tid & 7;
    int c0  = q * 4;
    int pr0 = tid >> 3;
    float acc = 0.f;

    for (int chunk = 0; chunk < 2; ++chunk) {
        __syncthreads();
        float4 a4 = *(const float4*)&ab[chunk * 32 + c0];
        float4 b4 = *(const float4*)&ab[64 + chunk * 32 + c0];
        #pragma unroll
        for (int k = 0; k < 11; ++k) {
            int p = k * 32 + pr0;
            if (p < 324) {
                int y = p / 18, xx = p - y * 18;
                int gy = by * 16 + y - 1, gx = bx * 16 + xx - 1;
                bool inb = (gy >= 0 && gy < H_ && gx >= 0 && gx < W_);
                const float4* src = (const float4*)(
                    hin + ((size_t)(b * NPIX + (inb ? gy * W_ + gx : 0))) * 64 + chunk * 32 + c0);
                float4 v = *src;
                float4 o;
                o.x = inb ? fmaxf(fmaf(v.x, a4.x, b4.x), 0.f) : 0.f;
                o.y = inb ? fmaxf(fmaf(v.y, a4.y, b4.y), 0.f) : 0.f;
                o.z = inb ? fmaxf(fmaf(v.z, a4.z, b4.z), 0.f) : 0.f;
                o.w = inb ? fmaxf(fmaf(v.w, a4.w, b4.w), 0.f) : 0.f;
                *(float4*)&s_in[p * 36 + 4*q] = o;
            }
        }
        __syncthreads();

        #pragma unroll
        for (int u = 0; u < 8; ++u) {
            f32x4 wreg[4][3];
            #pragma unroll
            for (int e = 0; e < 4; ++e)
                #pragma unroll
                for (int g = 0; g < 3; ++g)
                    wreg[e][g] = *(const f32x4*)&s_w[(chunk * 32 + u * 4 + e) * 12 + g * 4];
            #pragma unroll
            for (int t = 0; t < 9; ++t) {
                int dr = t / 3, dc = t - dr * 3;
                const float4 hv = *(const float4*)&s_in[((py + dr) * 18 + px + dc) * 36 + 4 * u];
                acc = fmaf(hv.x, wreg[0][t >> 2][t & 3], acc);
                acc = fmaf(hv.y, wreg[1][t >> 2][t & 3], acc);
                acc = fmaf(hv.z, wreg[2][t >> 2][t & 3], acc);
                acc = fmaf(hv.w, wreg[3][t >> 2][t & 3], acc);
            }
        }
    }

    int gy = by * 16 + py, gx = bx * 16 + px;
    out[b * NPIX + gy * W_ + gx] = xpre - acc;
}

// ---------------------------------------------------------------------------
// launcher — ws: hA fp32 @0, hB fp32 @134217728 (NHWC layout)
// ---------------------------------------------------------------------------
extern "C" void kernel_launch(void* const* d_in, const int* in_sizes, int n_in,
                              void* d_out, int out_size, void* d_ws, size_t ws_size,
                              hipStream_t stream)
{
    const float* x        = (const float*)d_in[0];
    const float* w_init   = (const float*)d_in[1];
    const float* w_body   = (const float*)d_in[2];
    const float* bn_gamma = (const float*)d_in[3];
    const float* bn_beta  = (const float*)d_in[4];
    const float* w_final  = (const float*)d_in[5];
    float* out = (float*)d_out;

    char* wsb = (char*)d_ws;
    float* hA = (float*)wsb;
    float* hB = (float*)(wsb + 134217728ULL);

    init_ab_kernel <<<1, 64, 0, stream>>>();
    prepack_kernel <<<270, 256, 0, stream>>>(w_body);
    conv_init_kernel<<<dim3(8, 32, 8), 256, 0, stream>>>(x, w_init, hA);

    float* cur = hA;
    float* nxt = hB;
    for (int l = 0; l < 15; ++l) {
        conv_body_mfma<<<NBLK, 256, 0, stream>>>(cur, l, nxt);
        bn_finalize_kernel<<<64, 256, 0, stream>>>(bn_gamma + l * 64, bn_beta + l * 64);
        float* tp = cur; cur = nxt; nxt = tp;
    }
    conv_final_kernel<<<dim3(16, 16, 8), 256, 0, stream>>>(cur, w_final, x, out);
}